// Round 3
// baseline (541.307 us; speedup 1.0000x reference)
//
#include <hip/hip_runtime.h>
#include <math.h>

// Problem constants (fixed by the reference setup)
#define NTOT 32768
#define NB   64
#define NPB  512      // rows per segment
#define DQK  128
#define MF   256      // feature count m
#define DVV  256      // value dim

#define QK_SCALE   0.29730177875068026f   // 128^-0.25
#define INV_SQRT_M 0.0625f                // 1/sqrt(256)
#define EPS_PHI    1e-4f
#define EPS_NORM   1e-8f

// XOR swizzle on float4-slot index within a row: maps 4/8-way b128 bank
// conflicts (tx*8 column pattern) down to 2-way (free). Bijection within
// each block of 8 slots -> apply identically on LDS write and read.
#define SW(f4) ((f4) ^ (((f4) >> 3) & 1))

static __device__ __forceinline__ float red_max32(float v) {
    v = fmaxf(v, __shfl_xor(v, 1, 64));
    v = fmaxf(v, __shfl_xor(v, 2, 64));
    v = fmaxf(v, __shfl_xor(v, 4, 64));
    v = fmaxf(v, __shfl_xor(v, 8, 64));
    v = fmaxf(v, __shfl_xor(v, 16, 64));
    return v;
}
static __device__ __forceinline__ float red_sum32(float v) {
    v += __shfl_xor(v, 1, 64);
    v += __shfl_xor(v, 2, 64);
    v += __shfl_xor(v, 4, 64);
    v += __shfl_xor(v, 8, 64);
    v += __shfl_xor(v, 16, 64);
    return v;
}

// ---------------------------------------------------------------------------
// Kernel 1: U = (X * d^-1/4) @ omega  [64 rows x all 256 cols per block]
// 256 threads: tx = tid&31 (8 cols), ty = tid>>5 (8 rows). 8x8 micro.
//   IS_QUERY: out = Qp = (exp(U-h-rowmax)+eps)/sqrt(m); aux = norm = Qp.Ksum
//   else:     out = U - h; aux = rowmax(U)
// ---------------------------------------------------------------------------
template <bool IS_QUERY>
__global__ __launch_bounds__(256, 3) void phi_kernel(
    const float* __restrict__ X, const float* __restrict__ omega,
    const float* __restrict__ Ksum,
    float* __restrict__ out, float* __restrict__ aux)
{
    __shared__ __align__(16) float xs[64][128];   // row-major (reads are 2-way broadcast)
    __shared__ __align__(16) float oms[16][256];  // k-major omega chunk, swizzled
    __shared__ float KsS[256];

    const int tid = threadIdx.x;
    const int tx  = tid & 31;
    const int ty  = tid >> 5;
    const int row0 = blockIdx.x * 64;

    if (IS_QUERY) KsS[tid] = Ksum[(row0 >> 9) * MF + tid];

    // ---- stage X tile (64x128), scaled ----
    {
        const float4* Xv = (const float4*)(X + (size_t)row0 * DQK);
        #pragma unroll
        for (int j = 0; j < 8; ++j) {
            int idx = tid + 256 * j;
            int r = idx >> 5, c4 = idx & 31;
            float4 v = Xv[idx];
            v.x *= QK_SCALE; v.y *= QK_SCALE; v.z *= QK_SCALE; v.w *= QK_SCALE;
            *(float4*)&xs[r][c4 * 4] = v;
        }
    }

    float acc[8][8] = {};
    float h[8] = {};

    const float4* Ov = (const float4*)omega;
    float4 oreg[4];
    #pragma unroll
    for (int j = 0; j < 4; ++j) oreg[j] = Ov[tid + 256 * j];

    for (int c = 0; c < 8; ++c) {
        __syncthreads();
        #pragma unroll
        for (int j = 0; j < 4; ++j) {
            int idx = tid + 256 * j;
            *(float4*)&oms[idx >> 6][SW(idx & 63) * 4] = oreg[j];
        }
        __syncthreads();
        if (c < 7) {
            #pragma unroll
            for (int j = 0; j < 4; ++j)
                oreg[j] = Ov[(c + 1) * 1024 + tid + 256 * j];
        }
        const int kc = c * 16;
        #pragma unroll
        for (int kq = 0; kq < 4; ++kq) {
            float4 a4[8];
            #pragma unroll
            for (int i = 0; i < 8; ++i)
                a4[i] = *(const float4*)&xs[ty * 8 + i][kc + kq * 4];
            #pragma unroll
            for (int t = 0; t < 4; ++t) {
                const int kk = kq * 4 + t;
                float4 b0 = *(const float4*)&oms[kk][SW(tx * 2) * 4];
                float4 b1 = *(const float4*)&oms[kk][SW(tx * 2 + 1) * 4];
                float bv[8] = {b0.x, b0.y, b0.z, b0.w, b1.x, b1.y, b1.z, b1.w};
                #pragma unroll
                for (int i = 0; i < 8; ++i) {
                    const float av = ((const float*)&a4[i])[t];
                    h[i] = fmaf(av, av, h[i]);
                    #pragma unroll
                    for (int j = 0; j < 8; ++j)
                        acc[i][j] = fmaf(av, bv[j], acc[i][j]);
                }
            }
        }
    }

    #pragma unroll
    for (int i = 0; i < 8; ++i) {
        const int grow = row0 + ty * 8 + i;
        float mx = acc[i][0];
        #pragma unroll
        for (int j = 1; j < 8; ++j) mx = fmaxf(mx, acc[i][j]);
        mx = red_max32(mx);
        const float hv = 0.5f * h[i];

        if (IS_QUERY) {
            const float hm = hv + mx;
            float q[8];
            #pragma unroll
            for (int j = 0; j < 8; ++j)
                q[j] = (__expf(acc[i][j] - hm) + EPS_PHI) * INV_SQRT_M;
            float4 o0 = {q[0], q[1], q[2], q[3]};
            float4 o1 = {q[4], q[5], q[6], q[7]};
            *(float4*)&out[(size_t)grow * MF + tx * 8]     = o0;
            *(float4*)&out[(size_t)grow * MF + tx * 8 + 4] = o1;
            float np = 0.f;
            #pragma unroll
            for (int j = 0; j < 8; ++j) np = fmaf(q[j], KsS[tx * 8 + j], np);
            np = red_sum32(np);
            if (tx == 0) aux[grow] = np;
        } else {
            float4 o0 = {acc[i][0] - hv, acc[i][1] - hv, acc[i][2] - hv, acc[i][3] - hv};
            float4 o1 = {acc[i][4] - hv, acc[i][5] - hv, acc[i][6] - hv, acc[i][7] - hv};
            *(float4*)&out[(size_t)grow * MF + tx * 8]     = o0;
            *(float4*)&out[(size_t)grow * MF + tx * 8 + 4] = o1;
            if (tx == 0) aux[grow] = mx;
        }
    }
}

// ---------------------------------------------------------------------------
// Kernel 2: segmax[b] = max over 512 rows of rmax
// ---------------------------------------------------------------------------
__global__ __launch_bounds__(256) void segmax_kernel(
    const float* __restrict__ rmax, float* __restrict__ segmax)
{
    const int b = blockIdx.x, tid = threadIdx.x;
    float v = fmaxf(rmax[b * NPB + tid], rmax[b * NPB + 256 + tid]);
    v = red_max32(v);
    v = fmaxf(v, __shfl_xor(v, 32, 64));
    __shared__ float red[4];
    if ((tid & 63) == 0) red[tid >> 6] = v;
    __syncthreads();
    if (tid == 0)
        segmax[b] = fmaxf(fmaxf(red[0], red[1]), fmaxf(red[2], red[3]));
}

// ---------------------------------------------------------------------------
// Kernel 3: partial KV: KVp[nt] = Kp[nt-slice]^T @ V[nt-slice].
// 128x128 tile, 8x8 micro, n-chunk 32, NS-way n-split for occupancy
// (NS blocks/CU instead of 1). Swizzled LDS (2-way max). vt==0 emits
// partial Ksum. grid.z = b*NS + nt.
// ---------------------------------------------------------------------------
template <int NS>
__global__ __launch_bounds__(256, 4) void kv_kernel(
    const float* __restrict__ A, const float* __restrict__ V,
    const float* __restrict__ segmax,
    float* __restrict__ KVp, float* __restrict__ Ksump)
{
    __shared__ __align__(16) float Kps[32][128];
    __shared__ __align__(16) float Vs[32][128];

    const int tid = threadIdx.x;
    const int tx = tid & 15, ty = tid >> 4;
    const int vt = blockIdx.x, mt = blockIdx.y;
    const int b  = blockIdx.z / NS;
    const int nt = blockIdx.z % NS;
    const int m0 = mt * 128, v0 = vt * 128;
    const size_t n0 = (size_t)b * NPB + (size_t)nt * (NPB / NS);
    const float smax = segmax[b];

    const int ln  = tid >> 5;     // 0..7
    const int lm4 = tid & 31;     // float4 column slot (logical)

    float acc[8][8] = {};
    float4 ks4 = {0.f, 0.f, 0.f, 0.f};

    float4 areg[4], vreg[4];
    #pragma unroll
    for (int j = 0; j < 4; ++j) {
        const size_t n = n0 + ln + 8 * j;
        areg[j] = *(const float4*)&A[n * MF + m0 + lm4 * 4];
        vreg[j] = *(const float4*)&V[n * DVV + v0 + lm4 * 4];
    }

    const int NCHUNK = (NPB / NS) / 32;
    for (int c = 0; c < NCHUNK; ++c) {
        __syncthreads();
        #pragma unroll
        for (int j = 0; j < 4; ++j) {
            float4 e;
            e.x = (__expf(areg[j].x - smax) + EPS_PHI) * INV_SQRT_M;
            e.y = (__expf(areg[j].y - smax) + EPS_PHI) * INV_SQRT_M;
            e.z = (__expf(areg[j].z - smax) + EPS_PHI) * INV_SQRT_M;
            e.w = (__expf(areg[j].w - smax) + EPS_PHI) * INV_SQRT_M;
            ks4.x += e.x; ks4.y += e.y; ks4.z += e.z; ks4.w += e.w;
            *(float4*)&Kps[ln + 8 * j][SW(lm4) * 4] = e;
            *(float4*)&Vs[ln + 8 * j][SW(lm4) * 4]  = vreg[j];
        }
        __syncthreads();
        if (c < NCHUNK - 1) {
            #pragma unroll
            for (int j = 0; j < 4; ++j) {
                const size_t n = n0 + (c + 1) * 32 + ln + 8 * j;
                areg[j] = *(const float4*)&A[n * MF + m0 + lm4 * 4];
                vreg[j] = *(const float4*)&V[n * DVV + v0 + lm4 * 4];
            }
        }
        #pragma unroll 8
        for (int kk = 0; kk < 32; ++kk) {
            float4 a0 = *(const float4*)&Kps[kk][SW(ty * 2) * 4];
            float4 a1 = *(const float4*)&Kps[kk][SW(ty * 2 + 1) * 4];
            float4 b0 = *(const float4*)&Vs[kk][SW(tx * 2) * 4];
            float4 b1 = *(const float4*)&Vs[kk][SW(tx * 2 + 1) * 4];
            float av[8] = {a0.x, a0.y, a0.z, a0.w, a1.x, a1.y, a1.z, a1.w};
            float bv[8] = {b0.x, b0.y, b0.z, b0.w, b1.x, b1.y, b1.z, b1.w};
            #pragma unroll
            for (int i = 0; i < 8; ++i)
                #pragma unroll
                for (int j = 0; j < 8; ++j)
                    acc[i][j] = fmaf(av[i], bv[j], acc[i][j]);
        }
    }

    float* KVo = KVp + (size_t)nt * NB * MF * DVV;
    #pragma unroll
    for (int i = 0; i < 8; ++i) {
        float4 o0 = {acc[i][0], acc[i][1], acc[i][2], acc[i][3]};
        float4 o1 = {acc[i][4], acc[i][5], acc[i][6], acc[i][7]};
        const size_t base = ((size_t)b * MF + m0 + ty * 8 + i) * DVV + v0 + tx * 8;
        *(float4*)&KVo[base]     = o0;
        *(float4*)&KVo[base + 4] = o1;
    }

    if (vt == 0) {
        __syncthreads();
        *(float4*)&Kps[ln][SW(lm4) * 4] = ks4;     // scratch [8][128]
        __syncthreads();
        if (tid < 128) {
            float s = 0.f;
            #pragma unroll
            for (int g = 0; g < 8; ++g)
                s += Kps[g][SW(tid >> 2) * 4 + (tid & 3)];
            Ksump[(size_t)nt * NB * MF + b * MF + m0 + tid] = s;
        }
    }
}

// ---------------------------------------------------------------------------
// Kernel 3b: reduce NS partials: KV = sum_nt KVp[nt], Ksum = sum_nt Ksump[nt].
// blocks [0,2048): KV (1M float4, 2/thread); blocks [2048,2064): Ksum.
// ---------------------------------------------------------------------------
template <int NS>
__global__ __launch_bounds__(256) void reduce_kernel(
    const float* __restrict__ KVp, const float* __restrict__ Ksump,
    float* __restrict__ KV, float* __restrict__ Ksum)
{
    const int tid = threadIdx.x;
    if (blockIdx.x < 2048) {
        const float4* p = (const float4*)KVp;
        float4* o = (float4*)KV;
        const int gid = blockIdx.x * 256 + tid;     // 0..524287
        #pragma unroll
        for (int j = 0; j < 2; ++j) {
            const size_t i = gid + 524288 * (size_t)j;   // 1,048,576 f4 total
            float4 a = p[i];
            #pragma unroll
            for (int s = 1; s < NS; ++s) {
                float4 bq = p[i + (size_t)s * 1048576];
                a.x += bq.x; a.y += bq.y; a.z += bq.z; a.w += bq.w;
            }
            o[i] = a;
        }
    } else {
        const float4* p = (const float4*)Ksump;
        float4* o = (float4*)Ksum;
        const int t = (blockIdx.x - 2048) * 256 + tid;   // 0..4095 f4
        float4 a = p[t];
        #pragma unroll
        for (int s = 1; s < NS; ++s) {
            float4 bq = p[t + s * 4096];
            a.x += bq.x; a.y += bq.y; a.z += bq.z; a.w += bq.w;
        }
        o[t] = a;
    }
}

// ---------------------------------------------------------------------------
// Kernel 4: out = (Qp @ KV[b]) / (norm + eps). 128 rows x 64 v per block,
// 8x4 micro with rows = ty + 16*i (consecutive rows per wave ->
// consecutive bank quads, conflict-free). grid (4,4,64) = 1024 blocks.
// ---------------------------------------------------------------------------
__global__ __launch_bounds__(256, 4) void out_kernel(
    const float* __restrict__ Qp, const float* __restrict__ KVm,
    const float* __restrict__ normv, float* __restrict__ out)
{
    __shared__ __align__(16) float Qs[128][36];   // row-major, stride 9 f4
    __shared__ __align__(16) float KVs[32][64];   // k-major
    __shared__ float nrmS[128];

    const int tid = threadIdx.x;
    const int tx = tid & 15, ty = tid >> 4;
    const int vt = blockIdx.x, rt = blockIdx.y, b = blockIdx.z;
    const int v0 = vt * 64;
    const int r0 = b * NPB + rt * 128;

    if (tid < 128) nrmS[tid] = normv[r0 + tid];

    const int qr  = tid >> 3;     // 0..31 (+32j)
    const int qm4 = tid & 7;
    const int kr  = tid >> 4;     // 0..15 (+16j)
    const int kc4 = tid & 15;

    float acc[8][4] = {};

    float4 qreg[4], kreg[2];
    #pragma unroll
    for (int j = 0; j < 4; ++j)
        qreg[j] = *(const float4*)&Qp[(size_t)(r0 + qr + 32 * j) * MF + qm4 * 4];
    #pragma unroll
    for (int j = 0; j < 2; ++j)
        kreg[j] = *(const float4*)&KVm[((size_t)b * MF + kr + 16 * j) * DVV + v0 + kc4 * 4];

    for (int c = 0; c < 8; ++c) {
        __syncthreads();
        #pragma unroll
        for (int j = 0; j < 4; ++j)
            *(float4*)&Qs[qr + 32 * j][qm4 * 4] = qreg[j];
        #pragma unroll
        for (int j = 0; j < 2; ++j)
            *(float4*)&KVs[kr + 16 * j][kc4 * 4] = kreg[j];
        __syncthreads();
        if (c < 7) {
            const int mc = (c + 1) * 32;
            #pragma unroll
            for (int j = 0; j < 4; ++j)
                qreg[j] = *(const float4*)&Qp[(size_t)(r0 + qr + 32 * j) * MF + mc + qm4 * 4];
            #pragma unroll
            for (int j = 0; j < 2; ++j)
                kreg[j] = *(const float4*)&KVm[((size_t)b * MF + mc + kr + 16 * j) * DVV + v0 + kc4 * 4];
        }
        #pragma unroll 4
        for (int kq = 0; kq < 8; ++kq) {
            float4 a4[8];
            #pragma unroll
            for (int i = 0; i < 8; ++i)
                a4[i] = *(const float4*)&Qs[ty + 16 * i][kq * 4];
            #pragma unroll
            for (int t = 0; t < 4; ++t) {
                float4 b0 = *(const float4*)&KVs[kq * 4 + t][tx * 4];
                float bv[4] = {b0.x, b0.y, b0.z, b0.w};
                #pragma unroll
                for (int i = 0; i < 8; ++i) {
                    const float av = ((const float*)&a4[i])[t];
                    #pragma unroll
                    for (int j = 0; j < 4; ++j)
                        acc[i][j] = fmaf(av, bv[j], acc[i][j]);
                }
            }
        }
    }

    #pragma unroll
    for (int i = 0; i < 8; ++i) {
        const int r = ty + 16 * i;
        const float inv = 1.0f / (nrmS[r] + EPS_NORM);
        float4 o = {acc[i][0] * inv, acc[i][1] * inv, acc[i][2] * inv, acc[i][3] * inv};
        *(float4*)&out[(size_t)(r0 + r) * DVV + v0 + tx * 4] = o;
    }
}

// ---------------------------------------------------------------------------
extern "C" void kernel_launch(void* const* d_in, const int* in_sizes, int n_in,
                              void* d_out, int out_size, void* d_ws, size_t ws_size,
                              hipStream_t stream)
{
    const float* Q     = (const float*)d_in[0];
    const float* K     = (const float*)d_in[1];
    const float* V     = (const float*)d_in[2];
    const float* omega = (const float*)d_in[3];
    float* out = (float*)d_out;

    // NS=4 needs ~101.3 MB of workspace; fall back to NS=2 (~67.6 MB,
    // within the footprint already proven to fit) if ws is small.
    const size_t KVSZ = (size_t)NB * MF * DVV;           // 4,194,304 floats
    const size_t need4 = ((size_t)NTOT * MF              // A
                        + 4 * KVSZ                       // KVp (Qp aliases)
                        + 5 * (size_t)NB * MF            // Ksump + Ksum
                        + 2 * NTOT + NB) * sizeof(float);
    const int NS = (ws_size >= need4) ? 4 : 2;

    float* ws    = (float*)d_ws;
    float* A     = ws;                                   // N*M; KV aliases after kv
    float* KV    = ws;                                   // aliases A (A dead post-kv)
    float* KVp   = A + (size_t)NTOT * MF;                // NS * B*M*DV
    float* Qp    = KVp;                                  // aliases KVp (dead post-reduce)
    float* Ksump = KVp + (size_t)NS * KVSZ;              // NS * B*M
    float* Ksum  = Ksump + (size_t)NS * NB * MF;         // B*M
    float* rmaxA = Ksum + (size_t)NB * MF;               // N
    float* smax  = rmaxA + NTOT;                         // B
    float* normv = smax + NB;                            // N

    phi_kernel<false><<<NTOT / 64, 256, 0, stream>>>(K, omega, (const float*)nullptr, A, rmaxA);
    segmax_kernel<<<NB, 256, 0, stream>>>(rmaxA, smax);
    if (NS == 4) {
        kv_kernel<4><<<dim3(2, 2, NB * 4), 256, 0, stream>>>(A, V, smax, KVp, Ksump);
        reduce_kernel<4><<<2064, 256, 0, stream>>>(KVp, Ksump, KV, Ksum);
    } else {
        kv_kernel<2><<<dim3(2, 2, NB * 2), 256, 0, stream>>>(A, V, smax, KVp, Ksump);
        reduce_kernel<2><<<2064, 256, 0, stream>>>(KVp, Ksump, KV, Ksum);
    }
    phi_kernel<true ><<<NTOT / 64, 256, 0, stream>>>(Q, omega, Ksum, Qp, normv);
    out_kernel<<<dim3(4, 4, NB), 256, 0, stream>>>(Qp, KV, normv, out);
}

// Round 4
// 447.263 us; speedup vs baseline: 1.2103x; 1.2103x over previous
//
#include <hip/hip_runtime.h>
#include <math.h>

// Problem constants (fixed by the reference setup)
#define NTOT 32768
#define NB   64
#define NPB  512      // rows per segment
#define DQK  128
#define MF   256      // feature count m
#define DVV  256      // value dim

#define QK_SCALE   0.29730177875068026f   // 128^-0.25
#define INV_SQRT_M 0.0625f                // 1/sqrt(256)
#define EPS_PHI    1e-4f
#define EPS_NORM   1e-8f

// XOR swizzle on float4-slot index within a row (kv_kernel only).
#define SW(f4) ((f4) ^ (((f4) >> 3) & 1))

static __device__ __forceinline__ float red_max32(float v) {
    v = fmaxf(v, __shfl_xor(v, 1, 64));
    v = fmaxf(v, __shfl_xor(v, 2, 64));
    v = fmaxf(v, __shfl_xor(v, 4, 64));
    v = fmaxf(v, __shfl_xor(v, 8, 64));
    v = fmaxf(v, __shfl_xor(v, 16, 64));
    return v;
}
static __device__ __forceinline__ float red_sum32(float v) {
    v += __shfl_xor(v, 1, 64);
    v += __shfl_xor(v, 2, 64);
    v += __shfl_xor(v, 4, 64);
    v += __shfl_xor(v, 8, 64);
    v += __shfl_xor(v, 16, 64);
    return v;
}

// ---------------------------------------------------------------------------
// Kernel 1: U = (X * d^-1/4) @ omega  [64 rows x all 256 cols per block]
// 256 threads: tx = tid&31, ty = tid>>5 (8 rows each). 8x8 micro; the 8
// columns per thread are slots {tx, tx+32} (f4) -> B-reads hit 32 distinct
// consecutive bank quads: conflict-free, no swizzle.
// NOTE: plain launch_bounds. Round 3's (256,3) squeezed VGPR to 84 and
// spilled ~450 MB/dispatch to scratch. Do not re-add a min-waves clause.
//   IS_QUERY: out = Qp = (exp(U-h-rowmax)+eps)/sqrt(m); aux = norm = Qp.Ksum
//   else:     out = U - h; aux = rowmax(U)
// ---------------------------------------------------------------------------
template <bool IS_QUERY>
__global__ __launch_bounds__(256) void phi_kernel(
    const float* __restrict__ X, const float* __restrict__ omega,
    const float* __restrict__ Ksum,
    float* __restrict__ out, float* __restrict__ aux)
{
    __shared__ __align__(16) float xs[64][132];   // padded: +1 f4 slot per row
    __shared__ __align__(16) float oms[32][256];  // 32-k-row omega chunk
    __shared__ float KsS[256];

    const int tid = threadIdx.x;
    const int tx  = tid & 31;
    const int ty  = tid >> 5;
    const int row0 = blockIdx.x * 64;

    if (IS_QUERY) KsS[tid] = Ksum[(row0 >> 9) * MF + tid];

    // ---- stage X tile (64x128), scaled ----
    {
        const float4* Xv = (const float4*)(X + (size_t)row0 * DQK);
        #pragma unroll
        for (int j = 0; j < 8; ++j) {
            int idx = tid + 256 * j;
            int r = idx >> 5, c4 = idx & 31;
            float4 v = Xv[idx];
            v.x *= QK_SCALE; v.y *= QK_SCALE; v.z *= QK_SCALE; v.w *= QK_SCALE;
            *(float4*)&xs[r][c4 * 4] = v;
        }
    }

    float acc[8][8] = {};
    float h[8] = {};

    // register prefetch of omega chunk 0 (32 k-rows x 256 = 2048 f4)
    const float4* Ov = (const float4*)omega;
    float4 oreg[8];
    #pragma unroll
    for (int j = 0; j < 8; ++j) oreg[j] = Ov[tid + 256 * j];

    for (int c = 0; c < 4; ++c) {
        __syncthreads();
        #pragma unroll
        for (int j = 0; j < 8; ++j) {
            int idx = tid + 256 * j;
            *(float4*)&oms[idx >> 6][(idx & 63) * 4] = oreg[j];
        }
        __syncthreads();
        if (c < 3) {
            #pragma unroll
            for (int j = 0; j < 8; ++j)
                oreg[j] = Ov[(c + 1) * 2048 + tid + 256 * j];
        }
        const int kc = c * 32;
        #pragma unroll
        for (int kq = 0; kq < 8; ++kq) {
            float4 a4[8];
            #pragma unroll
            for (int i = 0; i < 8; ++i)
                a4[i] = *(const float4*)&xs[ty * 8 + i][kc + kq * 4];
            #pragma unroll
            for (int t = 0; t < 4; ++t) {
                const int kk = kq * 4 + t;
                float4 b0 = *(const float4*)&oms[kk][tx * 4];
                float4 b1 = *(const float4*)&oms[kk][(tx + 32) * 4];
                float bv[8] = {b0.x, b0.y, b0.z, b0.w, b1.x, b1.y, b1.z, b1.w};
                #pragma unroll
                for (int i = 0; i < 8; ++i) {
                    const float av = ((const float*)&a4[i])[t];
                    h[i] = fmaf(av, av, h[i]);
                    #pragma unroll
                    for (int j = 0; j < 8; ++j)
                        acc[i][j] = fmaf(av, bv[j], acc[i][j]);
                }
            }
        }
    }

    // ---- epilogue: thread cols j<4 -> tx*4+j, j>=4 -> 128+tx*4+(j-4) ----
    #pragma unroll
    for (int i = 0; i < 8; ++i) {
        const int grow = row0 + ty * 8 + i;
        float mx = acc[i][0];
        #pragma unroll
        for (int j = 1; j < 8; ++j) mx = fmaxf(mx, acc[i][j]);
        mx = red_max32(mx);
        const float hv = 0.5f * h[i];

        if (IS_QUERY) {
            const float hm = hv + mx;
            float q[8];
            #pragma unroll
            for (int j = 0; j < 8; ++j)
                q[j] = (__expf(acc[i][j] - hm) + EPS_PHI) * INV_SQRT_M;
            float4 o0 = {q[0], q[1], q[2], q[3]};
            float4 o1 = {q[4], q[5], q[6], q[7]};
            *(float4*)&out[(size_t)grow * MF + tx * 4]       = o0;
            *(float4*)&out[(size_t)grow * MF + 128 + tx * 4] = o1;
            float np = 0.f;
            #pragma unroll
            for (int j = 0; j < 4; ++j) {
                np = fmaf(q[j],     KsS[tx * 4 + j],       np);
                np = fmaf(q[4 + j], KsS[128 + tx * 4 + j], np);
            }
            np = red_sum32(np);
            if (tx == 0) aux[grow] = np;
        } else {
            float4 o0 = {acc[i][0] - hv, acc[i][1] - hv, acc[i][2] - hv, acc[i][3] - hv};
            float4 o1 = {acc[i][4] - hv, acc[i][5] - hv, acc[i][6] - hv, acc[i][7] - hv};
            *(float4*)&out[(size_t)grow * MF + tx * 4]       = o0;
            *(float4*)&out[(size_t)grow * MF + 128 + tx * 4] = o1;
            if (tx == 0) aux[grow] = mx;
        }
    }
}

// ---------------------------------------------------------------------------
// Kernel 2: segmax[b] = max over 512 rows of rmax
// ---------------------------------------------------------------------------
__global__ __launch_bounds__(256) void segmax_kernel(
    const float* __restrict__ rmax, float* __restrict__ segmax)
{
    const int b = blockIdx.x, tid = threadIdx.x;
    float v = fmaxf(rmax[b * NPB + tid], rmax[b * NPB + 256 + tid]);
    v = red_max32(v);
    v = fmaxf(v, __shfl_xor(v, 32, 64));
    __shared__ float red[4];
    if ((tid & 63) == 0) red[tid >> 6] = v;
    __syncthreads();
    if (tid == 0)
        segmax[b] = fmaxf(fmaxf(red[0], red[1]), fmaxf(red[2], red[3]));
}

// ---------------------------------------------------------------------------
// Kernel 3: partial KV: KVp[nt] = Kp[nt-slice]^T @ V[nt-slice].
// 128x128 tile, 8x8 micro, n-chunk 32, NS-way n-split for occupancy.
// Swizzled LDS (2-way max). vt==0 emits partial Ksum. grid.z = b*NS + nt.
// ---------------------------------------------------------------------------
template <int NS>
__global__ __launch_bounds__(256, 4) void kv_kernel(
    const float* __restrict__ A, const float* __restrict__ V,
    const float* __restrict__ segmax,
    float* __restrict__ KVp, float* __restrict__ Ksump)
{
    __shared__ __align__(16) float Kps[32][128];
    __shared__ __align__(16) float Vs[32][128];

    const int tid = threadIdx.x;
    const int tx = tid & 15, ty = tid >> 4;
    const int vt = blockIdx.x, mt = blockIdx.y;
    const int b  = blockIdx.z / NS;
    const int nt = blockIdx.z % NS;
    const int m0 = mt * 128, v0 = vt * 128;
    const size_t n0 = (size_t)b * NPB + (size_t)nt * (NPB / NS);
    const float smax = segmax[b];

    const int ln  = tid >> 5;     // 0..7
    const int lm4 = tid & 31;     // float4 column slot (logical)

    float acc[8][8] = {};
    float4 ks4 = {0.f, 0.f, 0.f, 0.f};

    float4 areg[4], vreg[4];
    #pragma unroll
    for (int j = 0; j < 4; ++j) {
        const size_t n = n0 + ln + 8 * j;
        areg[j] = *(const float4*)&A[n * MF + m0 + lm4 * 4];
        vreg[j] = *(const float4*)&V[n * DVV + v0 + lm4 * 4];
    }

    const int NCHUNK = (NPB / NS) / 32;
    for (int c = 0; c < NCHUNK; ++c) {
        __syncthreads();
        #pragma unroll
        for (int j = 0; j < 4; ++j) {
            float4 e;
            e.x = (__expf(areg[j].x - smax) + EPS_PHI) * INV_SQRT_M;
            e.y = (__expf(areg[j].y - smax) + EPS_PHI) * INV_SQRT_M;
            e.z = (__expf(areg[j].z - smax) + EPS_PHI) * INV_SQRT_M;
            e.w = (__expf(areg[j].w - smax) + EPS_PHI) * INV_SQRT_M;
            ks4.x += e.x; ks4.y += e.y; ks4.z += e.z; ks4.w += e.w;
            *(float4*)&Kps[ln + 8 * j][SW(lm4) * 4] = e;
            *(float4*)&Vs[ln + 8 * j][SW(lm4) * 4]  = vreg[j];
        }
        __syncthreads();
        if (c < NCHUNK - 1) {
            #pragma unroll
            for (int j = 0; j < 4; ++j) {
                const size_t n = n0 + (c + 1) * 32 + ln + 8 * j;
                areg[j] = *(const float4*)&A[n * MF + m0 + lm4 * 4];
                vreg[j] = *(const float4*)&V[n * DVV + v0 + lm4 * 4];
            }
        }
        #pragma unroll 8
        for (int kk = 0; kk < 32; ++kk) {
            float4 a0 = *(const float4*)&Kps[kk][SW(ty * 2) * 4];
            float4 a1 = *(const float4*)&Kps[kk][SW(ty * 2 + 1) * 4];
            float4 b0 = *(const float4*)&Vs[kk][SW(tx * 2) * 4];
            float4 b1 = *(const float4*)&Vs[kk][SW(tx * 2 + 1) * 4];
            float av[8] = {a0.x, a0.y, a0.z, a0.w, a1.x, a1.y, a1.z, a1.w};
            float bv[8] = {b0.x, b0.y, b0.z, b0.w, b1.x, b1.y, b1.z, b1.w};
            #pragma unroll
            for (int i = 0; i < 8; ++i)
                #pragma unroll
                for (int j = 0; j < 8; ++j)
                    acc[i][j] = fmaf(av[i], bv[j], acc[i][j]);
        }
    }

    float* KVo = KVp + (size_t)nt * NB * MF * DVV;
    #pragma unroll
    for (int i = 0; i < 8; ++i) {
        float4 o0 = {acc[i][0], acc[i][1], acc[i][2], acc[i][3]};
        float4 o1 = {acc[i][4], acc[i][5], acc[i][6], acc[i][7]};
        const size_t base = ((size_t)b * MF + m0 + ty * 8 + i) * DVV + v0 + tx * 8;
        *(float4*)&KVo[base]     = o0;
        *(float4*)&KVo[base + 4] = o1;
    }

    if (vt == 0) {
        __syncthreads();
        *(float4*)&Kps[ln][SW(lm4) * 4] = ks4;     // scratch [8][128]
        __syncthreads();
        if (tid < 128) {
            float s = 0.f;
            #pragma unroll
            for (int g = 0; g < 8; ++g)
                s += Kps[g][SW(tid >> 2) * 4 + (tid & 3)];
            Ksump[(size_t)nt * NB * MF + b * MF + m0 + tid] = s;
        }
    }
}

// ---------------------------------------------------------------------------
// Kernel 3b: reduce NS partials: KV = sum_nt KVp[nt], Ksum = sum_nt Ksump[nt].
// ---------------------------------------------------------------------------
template <int NS>
__global__ __launch_bounds__(256) void reduce_kernel(
    const float* __restrict__ KVp, const float* __restrict__ Ksump,
    float* __restrict__ KV, float* __restrict__ Ksum)
{
    const int tid = threadIdx.x;
    if (blockIdx.x < 2048) {
        const float4* p = (const float4*)KVp;
        float4* o = (float4*)KV;
        const int gid = blockIdx.x * 256 + tid;
        #pragma unroll
        for (int j = 0; j < 2; ++j) {
            const size_t i = gid + 524288 * (size_t)j;
            float4 a = p[i];
            #pragma unroll
            for (int s = 1; s < NS; ++s) {
                float4 bq = p[i + (size_t)s * 1048576];
                a.x += bq.x; a.y += bq.y; a.z += bq.z; a.w += bq.w;
            }
            o[i] = a;
        }
    } else {
        const float4* p = (const float4*)Ksump;
        float4* o = (float4*)Ksum;
        const int t = (blockIdx.x - 2048) * 256 + tid;
        float4 a = p[t];
        #pragma unroll
        for (int s = 1; s < NS; ++s) {
            float4 bq = p[t + s * 4096];
            a.x += bq.x; a.y += bq.y; a.z += bq.z; a.w += bq.w;
        }
        o[t] = a;
    }
}

// ---------------------------------------------------------------------------
// Kernel 4: out = (Qp @ KV[b]) / (norm + eps). 128 rows x 64 v per block,
// 8x4 micro with rows = ty + 16*i. grid (4,4,64) = 1024 blocks.
// ---------------------------------------------------------------------------
__global__ __launch_bounds__(256, 4) void out_kernel(
    const float* __restrict__ Qp, const float* __restrict__ KVm,
    const float* __restrict__ normv, float* __restrict__ out)
{
    __shared__ __align__(16) float Qs[128][36];   // row-major, stride 9 f4
    __shared__ __align__(16) float KVs[32][64];   // k-major
    __shared__ float nrmS[128];

    const int tid = threadIdx.x;
    const int tx = tid & 15, ty = tid >> 4;
    const int vt = blockIdx.x, rt = blockIdx.y, b = blockIdx.z;
    const int v0 = vt * 64;
    const int r0 = b * NPB + rt * 128;

    if (tid < 128) nrmS[tid] = normv[r0 + tid];

    const int qr  = tid >> 3;     // 0..31 (+32j)
    const int qm4 = tid & 7;
    const int kr  = tid >> 4;     // 0..15 (+16j)
    const int kc4 = tid & 15;

    float acc[8][4] = {};

    float4 qreg[4], kreg[2];
    #pragma unroll
    for (int j = 0; j < 4; ++j)
        qreg[j] = *(const float4*)&Qp[(size_t)(r0 + qr + 32 * j) * MF + qm4 * 4];
    #pragma unroll
    for (int j = 0; j < 2; ++j)
        kreg[j] = *(const float4*)&KVm[((size_t)b * MF + kr + 16 * j) * DVV + v0 + kc4 * 4];

    for (int c = 0; c < 8; ++c) {
        __syncthreads();
        #pragma unroll
        for (int j = 0; j < 4; ++j)
            *(float4*)&Qs[qr + 32 * j][qm4 * 4] = qreg[j];
        #pragma unroll
        for (int j = 0; j < 2; ++j)
            *(float4*)&KVs[kr + 16 * j][kc4 * 4] = kreg[j];
        __syncthreads();
        if (c < 7) {
            const int mc = (c + 1) * 32;
            #pragma unroll
            for (int j = 0; j < 4; ++j)
                qreg[j] = *(const float4*)&Qp[(size_t)(r0 + qr + 32 * j) * MF + mc + qm4 * 4];
            #pragma unroll
            for (int j = 0; j < 2; ++j)
                kreg[j] = *(const float4*)&KVm[((size_t)b * MF + mc + kr + 16 * j) * DVV + v0 + kc4 * 4];
        }
        #pragma unroll 4
        for (int kq = 0; kq < 8; ++kq) {
            float4 a4[8];
            #pragma unroll
            for (int i = 0; i < 8; ++i)
                a4[i] = *(const float4*)&Qs[ty + 16 * i][kq * 4];
            #pragma unroll
            for (int t = 0; t < 4; ++t) {
                float4 b0 = *(const float4*)&KVs[kq * 4 + t][tx * 4];
                float bv[4] = {b0.x, b0.y, b0.z, b0.w};
                #pragma unroll
                for (int i = 0; i < 8; ++i) {
                    const float av = ((const float*)&a4[i])[t];
                    #pragma unroll
                    for (int j = 0; j < 4; ++j)
                        acc[i][j] = fmaf(av, bv[j], acc[i][j]);
                }
            }
        }
    }

    #pragma unroll
    for (int i = 0; i < 8; ++i) {
        const int r = ty + 16 * i;
        const float inv = 1.0f / (nrmS[r] + EPS_NORM);
        float4 o = {acc[i][0] * inv, acc[i][1] * inv, acc[i][2] * inv, acc[i][3] * inv};
        *(float4*)&out[(size_t)(r0 + r) * DVV + v0 + tx * 4] = o;
    }
}

// ---------------------------------------------------------------------------
extern "C" void kernel_launch(void* const* d_in, const int* in_sizes, int n_in,
                              void* d_out, int out_size, void* d_ws, size_t ws_size,
                              hipStream_t stream)
{
    const float* Q     = (const float*)d_in[0];
    const float* K     = (const float*)d_in[1];
    const float* V     = (const float*)d_in[2];
    const float* omega = (const float*)d_in[3];
    float* out = (float*)d_out;

    const size_t KVSZ = (size_t)NB * MF * DVV;           // 4,194,304 floats
    const size_t need4 = ((size_t)NTOT * MF
                        + 4 * KVSZ
                        + 5 * (size_t)NB * MF
                        + 2 * NTOT + NB) * sizeof(float);
    const int NS = (ws_size >= need4) ? 4 : 2;

    float* ws    = (float*)d_ws;
    float* A     = ws;                                   // N*M; KV aliases after kv
    float* KV    = ws;                                   // aliases A (A dead post-kv)
    float* KVp   = A + (size_t)NTOT * MF;                // NS * B*M*DV
    float* Qp    = KVp;                                  // aliases KVp (dead post-reduce)
    float* Ksump = KVp + (size_t)NS * KVSZ;              // NS * B*M
    float* Ksum  = Ksump + (size_t)NS * NB * MF;         // B*M
    float* rmaxA = Ksum + (size_t)NB * MF;               // N
    float* smax  = rmaxA + NTOT;                         // B
    float* normv = smax + NB;                            // N

    phi_kernel<false><<<NTOT / 64, 256, 0, stream>>>(K, omega, (const float*)nullptr, A, rmaxA);
    segmax_kernel<<<NB, 256, 0, stream>>>(rmaxA, smax);
    if (NS == 4) {
        kv_kernel<4><<<dim3(2, 2, NB * 4), 256, 0, stream>>>(A, V, smax, KVp, Ksump);
        reduce_kernel<4><<<2064, 256, 0, stream>>>(KVp, Ksump, KV, Ksum);
    } else {
        kv_kernel<2><<<dim3(2, 2, NB * 2), 256, 0, stream>>>(A, V, smax, KVp, Ksump);
        reduce_kernel<2><<<2064, 256, 0, stream>>>(KVp, Ksump, KV, Ksum);
    }
    phi_kernel<true ><<<NTOT / 64, 256, 0, stream>>>(Q, omega, Ksum, Qp, normv);
    out_kernel<<<dim3(4, 4, NB), 256, 0, stream>>>(Qp, KV, normv, out);
}

// Round 5
// 397.739 us; speedup vs baseline: 1.3610x; 1.1245x over previous
//
#include <hip/hip_runtime.h>
#include <math.h>

// Problem constants (fixed by the reference setup)
#define NTOT 32768
#define NB   64
#define NPB  512      // rows per segment
#define DQK  128
#define MF   256      // feature count m
#define DVV  256      // value dim

#define QK_SCALE   0.29730177875068026f   // 128^-0.25
#define INV_SQRT_M 0.0625f                // 1/sqrt(256)
#define EPS_PHI    1e-4f
#define EPS_NORM   1e-8f

// XOR swizzle on float4-slot index within a row (kv_kernel only).
#define SW(f4) ((f4) ^ (((f4) >> 3) & 1))

// ============================================================================
// LESSON (rounds 3+4): NEVER add a min-waves clause (__launch_bounds__(256,N))
// to these register-heavy GEMM bodies. (256,3) squeezed phi to 84 VGPR and
// (256,4) squeezed kv/out to 64/60 VGPR -> hundreds of MB of scratch spill
// per dispatch (WRITE_SIZE 179-345 MB vs ~35 MB real). Natural allocation
// (~100 VGPR, round 2 evidence) gives 4-5 blocks/CU by itself.
// ============================================================================

static __device__ __forceinline__ float red_max32(float v) {
    v = fmaxf(v, __shfl_xor(v, 1, 64));
    v = fmaxf(v, __shfl_xor(v, 2, 64));
    v = fmaxf(v, __shfl_xor(v, 4, 64));
    v = fmaxf(v, __shfl_xor(v, 8, 64));
    v = fmaxf(v, __shfl_xor(v, 16, 64));
    return v;
}
static __device__ __forceinline__ float red_sum32(float v) {
    v += __shfl_xor(v, 1, 64);
    v += __shfl_xor(v, 2, 64);
    v += __shfl_xor(v, 4, 64);
    v += __shfl_xor(v, 8, 64);
    v += __shfl_xor(v, 16, 64);
    return v;
}

// ---------------------------------------------------------------------------
// Kernel 1: U = (X * d^-1/4) @ omega  [64 rows x all 256 cols per block]
// 256 threads: tx = tid&31, ty = tid>>5 (8 rows each). 8x8 micro; the 8
// columns per thread are slots {tx, tx+32} (f4) -> B-reads conflict-free.
//   IS_QUERY: out = Qp = (exp(U-h-rowmax)+eps)/sqrt(m); aux = norm = Qp.Ksum
//   else:     out = U - h; aux = rowmax(U)
// ---------------------------------------------------------------------------
template <bool IS_QUERY>
__global__ __launch_bounds__(256) void phi_kernel(
    const float* __restrict__ X, const float* __restrict__ omega,
    const float* __restrict__ Ksum,
    float* __restrict__ out, float* __restrict__ aux)
{
    __shared__ __align__(16) float xs[64][132];   // padded: +1 f4 slot per row
    __shared__ __align__(16) float oms[32][256];  // 32-k-row omega chunk
    __shared__ float KsS[256];

    const int tid = threadIdx.x;
    const int tx  = tid & 31;
    const int ty  = tid >> 5;
    const int row0 = blockIdx.x * 64;

    if (IS_QUERY) KsS[tid] = Ksum[(row0 >> 9) * MF + tid];

    // ---- stage X tile (64x128), scaled ----
    {
        const float4* Xv = (const float4*)(X + (size_t)row0 * DQK);
        #pragma unroll
        for (int j = 0; j < 8; ++j) {
            int idx = tid + 256 * j;
            int r = idx >> 5, c4 = idx & 31;
            float4 v = Xv[idx];
            v.x *= QK_SCALE; v.y *= QK_SCALE; v.z *= QK_SCALE; v.w *= QK_SCALE;
            *(float4*)&xs[r][c4 * 4] = v;
        }
    }

    float acc[8][8] = {};
    float h[8] = {};

    // register prefetch of omega chunk 0 (32 k-rows x 256 = 2048 f4)
    const float4* Ov = (const float4*)omega;
    float4 oreg[8];
    #pragma unroll
    for (int j = 0; j < 8; ++j) oreg[j] = Ov[tid + 256 * j];

    for (int c = 0; c < 4; ++c) {
        __syncthreads();
        #pragma unroll
        for (int j = 0; j < 8; ++j) {
            int idx = tid + 256 * j;
            *(float4*)&oms[idx >> 6][(idx & 63) * 4] = oreg[j];
        }
        __syncthreads();
        if (c < 3) {
            #pragma unroll
            for (int j = 0; j < 8; ++j)
                oreg[j] = Ov[(c + 1) * 2048 + tid + 256 * j];
        }
        const int kc = c * 32;
        #pragma unroll
        for (int kq = 0; kq < 8; ++kq) {
            float4 a4[8];
            #pragma unroll
            for (int i = 0; i < 8; ++i)
                a4[i] = *(const float4*)&xs[ty * 8 + i][kc + kq * 4];
            #pragma unroll
            for (int t = 0; t < 4; ++t) {
                const int kk = kq * 4 + t;
                float4 b0 = *(const float4*)&oms[kk][tx * 4];
                float4 b1 = *(const float4*)&oms[kk][(tx + 32) * 4];
                float bv[8] = {b0.x, b0.y, b0.z, b0.w, b1.x, b1.y, b1.z, b1.w};
                #pragma unroll
                for (int i = 0; i < 8; ++i) {
                    const float av = ((const float*)&a4[i])[t];
                    h[i] = fmaf(av, av, h[i]);
                    #pragma unroll
                    for (int j = 0; j < 8; ++j)
                        acc[i][j] = fmaf(av, bv[j], acc[i][j]);
                }
            }
        }
    }

    // ---- epilogue: thread cols j<4 -> tx*4+j, j>=4 -> 128+tx*4+(j-4) ----
    #pragma unroll
    for (int i = 0; i < 8; ++i) {
        const int grow = row0 + ty * 8 + i;
        float mx = acc[i][0];
        #pragma unroll
        for (int j = 1; j < 8; ++j) mx = fmaxf(mx, acc[i][j]);
        mx = red_max32(mx);
        const float hv = 0.5f * h[i];

        if (IS_QUERY) {
            const float hm = hv + mx;
            float q[8];
            #pragma unroll
            for (int j = 0; j < 8; ++j)
                q[j] = (__expf(acc[i][j] - hm) + EPS_PHI) * INV_SQRT_M;
            float4 o0 = {q[0], q[1], q[2], q[3]};
            float4 o1 = {q[4], q[5], q[6], q[7]};
            *(float4*)&out[(size_t)grow * MF + tx * 4]       = o0;
            *(float4*)&out[(size_t)grow * MF + 128 + tx * 4] = o1;
            float np = 0.f;
            #pragma unroll
            for (int j = 0; j < 4; ++j) {
                np = fmaf(q[j],     KsS[tx * 4 + j],       np);
                np = fmaf(q[4 + j], KsS[128 + tx * 4 + j], np);
            }
            np = red_sum32(np);
            if (tx == 0) aux[grow] = np;
        } else {
            float4 o0 = {acc[i][0] - hv, acc[i][1] - hv, acc[i][2] - hv, acc[i][3] - hv};
            float4 o1 = {acc[i][4] - hv, acc[i][5] - hv, acc[i][6] - hv, acc[i][7] - hv};
            *(float4*)&out[(size_t)grow * MF + tx * 4]       = o0;
            *(float4*)&out[(size_t)grow * MF + 128 + tx * 4] = o1;
            if (tx == 0) aux[grow] = mx;
        }
    }
}

// ---------------------------------------------------------------------------
// Kernel 2: segmax[b] = max over 512 rows of rmax
// ---------------------------------------------------------------------------
__global__ __launch_bounds__(256) void segmax_kernel(
    const float* __restrict__ rmax, float* __restrict__ segmax)
{
    const int b = blockIdx.x, tid = threadIdx.x;
    float v = fmaxf(rmax[b * NPB + tid], rmax[b * NPB + 256 + tid]);
    v = red_max32(v);
    v = fmaxf(v, __shfl_xor(v, 32, 64));
    __shared__ float red[4];
    if ((tid & 63) == 0) red[tid >> 6] = v;
    __syncthreads();
    if (tid == 0)
        segmax[b] = fmaxf(fmaxf(red[0], red[1]), fmaxf(red[2], red[3]));
}

// ---------------------------------------------------------------------------
// Kernel 3: partial KV: KVp[nt] = Kp[nt-slice]^T @ V[nt-slice].
// 128x128 tile, 8x8 micro, n-chunk 32, NS-way n-split for occupancy.
// PLAIN launch bounds (see LESSON above). Swizzled LDS. vt==0 emits
// partial Ksum. grid.z = b*NS + nt.
// ---------------------------------------------------------------------------
template <int NS>
__global__ __launch_bounds__(256) void kv_kernel(
    const float* __restrict__ A, const float* __restrict__ V,
    const float* __restrict__ segmax,
    float* __restrict__ KVp, float* __restrict__ Ksump)
{
    __shared__ __align__(16) float Kps[32][128];
    __shared__ __align__(16) float Vs[32][128];

    const int tid = threadIdx.x;
    const int tx = tid & 15, ty = tid >> 4;
    const int vt = blockIdx.x, mt = blockIdx.y;
    const int b  = blockIdx.z / NS;
    const int nt = blockIdx.z % NS;
    const int m0 = mt * 128, v0 = vt * 128;
    const size_t n0 = (size_t)b * NPB + (size_t)nt * (NPB / NS);
    const float smax = segmax[b];

    const int ln  = tid >> 5;     // 0..7
    const int lm4 = tid & 31;     // float4 column slot (logical)

    float acc[8][8] = {};
    float4 ks4 = {0.f, 0.f, 0.f, 0.f};

    float4 areg[4], vreg[4];
    #pragma unroll
    for (int j = 0; j < 4; ++j) {
        const size_t n = n0 + ln + 8 * j;
        areg[j] = *(const float4*)&A[n * MF + m0 + lm4 * 4];
        vreg[j] = *(const float4*)&V[n * DVV + v0 + lm4 * 4];
    }

    const int NCHUNK = (NPB / NS) / 32;
    for (int c = 0; c < NCHUNK; ++c) {
        __syncthreads();
        #pragma unroll
        for (int j = 0; j < 4; ++j) {
            float4 e;
            e.x = (__expf(areg[j].x - smax) + EPS_PHI) * INV_SQRT_M;
            e.y = (__expf(areg[j].y - smax) + EPS_PHI) * INV_SQRT_M;
            e.z = (__expf(areg[j].z - smax) + EPS_PHI) * INV_SQRT_M;
            e.w = (__expf(areg[j].w - smax) + EPS_PHI) * INV_SQRT_M;
            ks4.x += e.x; ks4.y += e.y; ks4.z += e.z; ks4.w += e.w;
            *(float4*)&Kps[ln + 8 * j][SW(lm4) * 4] = e;
            *(float4*)&Vs[ln + 8 * j][SW(lm4) * 4]  = vreg[j];
        }
        __syncthreads();
        if (c < NCHUNK - 1) {
            #pragma unroll
            for (int j = 0; j < 4; ++j) {
                const size_t n = n0 + (c + 1) * 32 + ln + 8 * j;
                areg[j] = *(const float4*)&A[n * MF + m0 + lm4 * 4];
                vreg[j] = *(const float4*)&V[n * DVV + v0 + lm4 * 4];
            }
        }
        #pragma unroll 8
        for (int kk = 0; kk < 32; ++kk) {
            float4 a0 = *(const float4*)&Kps[kk][SW(ty * 2) * 4];
            float4 a1 = *(const float4*)&Kps[kk][SW(ty * 2 + 1) * 4];
            float4 b0 = *(const float4*)&Vs[kk][SW(tx * 2) * 4];
            float4 b1 = *(const float4*)&Vs[kk][SW(tx * 2 + 1) * 4];
            float av[8] = {a0.x, a0.y, a0.z, a0.w, a1.x, a1.y, a1.z, a1.w};
            float bv[8] = {b0.x, b0.y, b0.z, b0.w, b1.x, b1.y, b1.z, b1.w};
            #pragma unroll
            for (int i = 0; i < 8; ++i)
                #pragma unroll
                for (int j = 0; j < 8; ++j)
                    acc[i][j] = fmaf(av[i], bv[j], acc[i][j]);
        }
    }

    float* KVo = KVp + (size_t)nt * NB * MF * DVV;
    #pragma unroll
    for (int i = 0; i < 8; ++i) {
        float4 o0 = {acc[i][0], acc[i][1], acc[i][2], acc[i][3]};
        float4 o1 = {acc[i][4], acc[i][5], acc[i][6], acc[i][7]};
        const size_t base = ((size_t)b * MF + m0 + ty * 8 + i) * DVV + v0 + tx * 8;
        *(float4*)&KVo[base]     = o0;
        *(float4*)&KVo[base + 4] = o1;
    }

    if (vt == 0) {
        __syncthreads();
        *(float4*)&Kps[ln][SW(lm4) * 4] = ks4;     // scratch [8][128]
        __syncthreads();
        if (tid < 128) {
            float s = 0.f;
            #pragma unroll
            for (int g = 0; g < 8; ++g)
                s += Kps[g][SW(tid >> 2) * 4 + (tid & 3)];
            Ksump[(size_t)nt * NB * MF + b * MF + m0 + tid] = s;
        }
    }
}

// ---------------------------------------------------------------------------
// Kernel 3b: reduce NS partials: KV = sum_nt KVp[nt], Ksum = sum_nt Ksump[nt].
// ---------------------------------------------------------------------------
template <int NS>
__global__ __launch_bounds__(256) void reduce_kernel(
    const float* __restrict__ KVp, const float* __restrict__ Ksump,
    float* __restrict__ KV, float* __restrict__ Ksum)
{
    const int tid = threadIdx.x;
    if (blockIdx.x < 2048) {
        const float4* p = (const float4*)KVp;
        float4* o = (float4*)KV;
        const int gid = blockIdx.x * 256 + tid;
        #pragma unroll
        for (int j = 0; j < 2; ++j) {
            const size_t i = gid + 524288 * (size_t)j;
            float4 a = p[i];
            #pragma unroll
            for (int s = 1; s < NS; ++s) {
                float4 bq = p[i + (size_t)s * 1048576];
                a.x += bq.x; a.y += bq.y; a.z += bq.z; a.w += bq.w;
            }
            o[i] = a;
        }
    } else {
        const float4* p = (const float4*)Ksump;
        float4* o = (float4*)Ksum;
        const int t = (blockIdx.x - 2048) * 256 + tid;
        float4 a = p[t];
        #pragma unroll
        for (int s = 1; s < NS; ++s) {
            float4 bq = p[t + s * 4096];
            a.x += bq.x; a.y += bq.y; a.z += bq.z; a.w += bq.w;
        }
        o[t] = a;
    }
}

// ---------------------------------------------------------------------------
// Kernel 4: out = (Qp @ KV[b]) / (norm + eps). 128 rows x 64 v per block,
// 8x4 micro with rows = ty + 16*i (consecutive bank quads, conflict-free).
// PLAIN launch bounds (see LESSON above). grid (4,4,64) = 1024 blocks.
// ---------------------------------------------------------------------------
__global__ __launch_bounds__(256) void out_kernel(
    const float* __restrict__ Qp, const float* __restrict__ KVm,
    const float* __restrict__ normv, float* __restrict__ out)
{
    __shared__ __align__(16) float Qs[128][36];   // row-major, stride 9 f4
    __shared__ __align__(16) float KVs[32][64];   // k-major
    __shared__ float nrmS[128];

    const int tid = threadIdx.x;
    const int tx = tid & 15, ty = tid >> 4;
    const int vt = blockIdx.x, rt = blockIdx.y, b = blockIdx.z;
    const int v0 = vt * 64;
    const int r0 = b * NPB + rt * 128;

    if (tid < 128) nrmS[tid] = normv[r0 + tid];

    const int qr  = tid >> 3;     // 0..31 (+32j)
    const int qm4 = tid & 7;
    const int kr  = tid >> 4;     // 0..15 (+16j)
    const int kc4 = tid & 15;

    float acc[8][4] = {};

    float4 qreg[4], kreg[2];
    #pragma unroll
    for (int j = 0; j < 4; ++j)
        qreg[j] = *(const float4*)&Qp[(size_t)(r0 + qr + 32 * j) * MF + qm4 * 4];
    #pragma unroll
    for (int j = 0; j < 2; ++j)
        kreg[j] = *(const float4*)&KVm[((size_t)b * MF + kr + 16 * j) * DVV + v0 + kc4 * 4];

    for (int c = 0; c < 8; ++c) {
        __syncthreads();
        #pragma unroll
        for (int j = 0; j < 4; ++j)
            *(float4*)&Qs[qr + 32 * j][qm4 * 4] = qreg[j];
        #pragma unroll
        for (int j = 0; j < 2; ++j)
            *(float4*)&KVs[kr + 16 * j][kc4 * 4] = kreg[j];
        __syncthreads();
        if (c < 7) {
            const int mc = (c + 1) * 32;
            #pragma unroll
            for (int j = 0; j < 4; ++j)
                qreg[j] = *(const float4*)&Qp[(size_t)(r0 + qr + 32 * j) * MF + mc + qm4 * 4];
            #pragma unroll
            for (int j = 0; j < 2; ++j)
                kreg[j] = *(const float4*)&KVm[((size_t)b * MF + mc + kr + 16 * j) * DVV + v0 + kc4 * 4];
        }
        #pragma unroll 4
        for (int kq = 0; kq < 8; ++kq) {
            float4 a4[8];
            #pragma unroll
            for (int i = 0; i < 8; ++i)
                a4[i] = *(const float4*)&Qs[ty + 16 * i][kq * 4];
            #pragma unroll
            for (int t = 0; t < 4; ++t) {
                float4 b0 = *(const float4*)&KVs[kq * 4 + t][tx * 4];
                float bv[4] = {b0.x, b0.y, b0.z, b0.w};
                #pragma unroll
                for (int i = 0; i < 8; ++i) {
                    const float av = ((const float*)&a4[i])[t];
                    #pragma unroll
                    for (int j = 0; j < 4; ++j)
                        acc[i][j] = fmaf(av, bv[j], acc[i][j]);
                }
            }
        }
    }

    #pragma unroll
    for (int i = 0; i < 8; ++i) {
        const int r = ty + 16 * i;
        const float inv = 1.0f / (nrmS[r] + EPS_NORM);
        float4 o = {acc[i][0] * inv, acc[i][1] * inv, acc[i][2] * inv, acc[i][3] * inv};
        *(float4*)&out[(size_t)(r0 + r) * DVV + v0 + tx * 4] = o;
    }
}

// ---------------------------------------------------------------------------
extern "C" void kernel_launch(void* const* d_in, const int* in_sizes, int n_in,
                              void* d_out, int out_size, void* d_ws, size_t ws_size,
                              hipStream_t stream)
{
    const float* Q     = (const float*)d_in[0];
    const float* K     = (const float*)d_in[1];
    const float* V     = (const float*)d_in[2];
    const float* omega = (const float*)d_in[3];
    float* out = (float*)d_out;

    const size_t KVSZ = (size_t)NB * MF * DVV;           // 4,194,304 floats
    const size_t need4 = ((size_t)NTOT * MF
                        + 4 * KVSZ
                        + 5 * (size_t)NB * MF
                        + 2 * NTOT + NB) * sizeof(float);
    const int NS = (ws_size >= need4) ? 4 : 2;

    float* ws    = (float*)d_ws;
    float* A     = ws;                                   // N*M; KV aliases after kv
    float* KV    = ws;                                   // aliases A (A dead post-kv)
    float* KVp   = A + (size_t)NTOT * MF;                // NS * B*M*DV
    float* Qp    = KVp;                                  // aliases KVp (dead post-reduce)
    float* Ksump = KVp + (size_t)NS * KVSZ;              // NS * B*M
    float* Ksum  = Ksump + (size_t)NS * NB * MF;         // B*M
    float* rmaxA = Ksum + (size_t)NB * MF;               // N
    float* smax  = rmaxA + NTOT;                         // B
    float* normv = smax + NB;                            // N

    phi_kernel<false><<<NTOT / 64, 256, 0, stream>>>(K, omega, (const float*)nullptr, A, rmaxA);
    segmax_kernel<<<NB, 256, 0, stream>>>(rmaxA, smax);
    if (NS == 4) {
        kv_kernel<4><<<dim3(2, 2, NB * 4), 256, 0, stream>>>(A, V, smax, KVp, Ksump);
        reduce_kernel<4><<<2064, 256, 0, stream>>>(KVp, Ksump, KV, Ksum);
    } else {
        kv_kernel<2><<<dim3(2, 2, NB * 2), 256, 0, stream>>>(A, V, smax, KVp, Ksump);
        reduce_kernel<2><<<2064, 256, 0, stream>>>(KVp, Ksump, KV, Ksum);
    }
    phi_kernel<true ><<<NTOT / 64, 256, 0, stream>>>(Q, omega, Ksum, Qp, normv);
    out_kernel<<<dim3(4, 4, NB), 256, 0, stream>>>(Qp, KV, normv, out);
}

// Round 6
// 375.929 us; speedup vs baseline: 1.4399x; 1.0580x over previous
//
#include <hip/hip_runtime.h>
#include <math.h>

// Problem constants (fixed by the reference setup)
#define NTOT 32768
#define NB   64
#define NPB  512      // rows per segment
#define DQK  128
#define MF   256      // feature count m
#define DVV  256      // value dim

#define QK_SCALE   0.29730177875068026f   // 128^-0.25
#define INV_SQRT_M 0.0625f                // 1/sqrt(256)
#define EPS_PHI    1e-4f
#define EPS_NORM   1e-8f

// XOR swizzle on float4-slot index within a row (kv_kernel only).
#define SW(f4) ((f4) ^ (((f4) >> 3) & 1))

// ============================================================================
// LESSONS (rounds 3-5):
// 1. NEVER add a min-waves clause (__launch_bounds__(256,N)) to these
//    register-heavy GEMM bodies -> forced VGPR squeeze -> scratch spill
//    (WRITE_SIZE 179-345 MB vs ~35 MB real).
// 2. The allocator's VGPR budget follows the LDS-implied occupancy target:
//    budget ~= 512 / floor(160KiB / LDS_bytes) regs. kv: 32 KB LDS -> 5
//    blocks -> budget 102 -> VGPR 100, clean. Round-5 out: 27 KB LDS ->
//    6-block target -> squeezed to 60 VGPR -> 194 MB spill. KEEP GEMM-BODY
//    LDS >= ~33 KB so the budget lands at >=102 regs.
// ============================================================================

static __device__ __forceinline__ float red_max32(float v) {
    v = fmaxf(v, __shfl_xor(v, 1, 64));
    v = fmaxf(v, __shfl_xor(v, 2, 64));
    v = fmaxf(v, __shfl_xor(v, 4, 64));
    v = fmaxf(v, __shfl_xor(v, 8, 64));
    v = fmaxf(v, __shfl_xor(v, 16, 64));
    return v;
}
static __device__ __forceinline__ float red_sum32(float v) {
    v += __shfl_xor(v, 1, 64);
    v += __shfl_xor(v, 2, 64);
    v += __shfl_xor(v, 4, 64);
    v += __shfl_xor(v, 8, 64);
    v += __shfl_xor(v, 16, 64);
    return v;
}

// ---------------------------------------------------------------------------
// Kernel 1: U = (X * d^-1/4) @ omega  [64 rows x all 256 cols per block]
// 256 threads: tx = tid&31, ty = tid>>5 (8 rows each). 8x8 micro; the 8
// columns per thread are slots {tx, tx+32} (f4) -> B-reads conflict-free.
//   IS_QUERY: out = Qp = (exp(U-h-rowmax)+eps)/sqrt(m); aux = norm = Qp.Ksum
//   else:     out = U - h; aux = rowmax(U)
// ---------------------------------------------------------------------------
template <bool IS_QUERY>
__global__ __launch_bounds__(256) void phi_kernel(
    const float* __restrict__ X, const float* __restrict__ omega,
    const float* __restrict__ Ksum,
    float* __restrict__ out, float* __restrict__ aux)
{
    __shared__ __align__(16) float xs[64][132];   // padded: +1 f4 slot per row
    __shared__ __align__(16) float oms[32][256];  // 32-k-row omega chunk
    __shared__ float KsS[256];

    const int tid = threadIdx.x;
    const int tx  = tid & 31;
    const int ty  = tid >> 5;
    const int row0 = blockIdx.x * 64;

    if (IS_QUERY) KsS[tid] = Ksum[(row0 >> 9) * MF + tid];

    // ---- stage X tile (64x128), scaled ----
    {
        const float4* Xv = (const float4*)(X + (size_t)row0 * DQK);
        #pragma unroll
        for (int j = 0; j < 8; ++j) {
            int idx = tid + 256 * j;
            int r = idx >> 5, c4 = idx & 31;
            float4 v = Xv[idx];
            v.x *= QK_SCALE; v.y *= QK_SCALE; v.z *= QK_SCALE; v.w *= QK_SCALE;
            *(float4*)&xs[r][c4 * 4] = v;
        }
    }

    float acc[8][8] = {};
    float h[8] = {};

    // register prefetch of omega chunk 0 (32 k-rows x 256 = 2048 f4)
    const float4* Ov = (const float4*)omega;
    float4 oreg[8];
    #pragma unroll
    for (int j = 0; j < 8; ++j) oreg[j] = Ov[tid + 256 * j];

    for (int c = 0; c < 4; ++c) {
        __syncthreads();
        #pragma unroll
        for (int j = 0; j < 8; ++j) {
            int idx = tid + 256 * j;
            *(float4*)&oms[idx >> 6][(idx & 63) * 4] = oreg[j];
        }
        __syncthreads();
        if (c < 3) {
            #pragma unroll
            for (int j = 0; j < 8; ++j)
                oreg[j] = Ov[(c + 1) * 2048 + tid + 256 * j];
        }
        const int kc = c * 32;
        #pragma unroll
        for (int kq = 0; kq < 8; ++kq) {
            float4 a4[8];
            #pragma unroll
            for (int i = 0; i < 8; ++i)
                a4[i] = *(const float4*)&xs[ty * 8 + i][kc + kq * 4];
            #pragma unroll
            for (int t = 0; t < 4; ++t) {
                const int kk = kq * 4 + t;
                float4 b0 = *(const float4*)&oms[kk][tx * 4];
                float4 b1 = *(const float4*)&oms[kk][(tx + 32) * 4];
                float bv[8] = {b0.x, b0.y, b0.z, b0.w, b1.x, b1.y, b1.z, b1.w};
                #pragma unroll
                for (int i = 0; i < 8; ++i) {
                    const float av = ((const float*)&a4[i])[t];
                    h[i] = fmaf(av, av, h[i]);
                    #pragma unroll
                    for (int j = 0; j < 8; ++j)
                        acc[i][j] = fmaf(av, bv[j], acc[i][j]);
                }
            }
        }
    }

    // ---- epilogue: thread cols j<4 -> tx*4+j, j>=4 -> 128+tx*4+(j-4) ----
    #pragma unroll
    for (int i = 0; i < 8; ++i) {
        const int grow = row0 + ty * 8 + i;
        float mx = acc[i][0];
        #pragma unroll
        for (int j = 1; j < 8; ++j) mx = fmaxf(mx, acc[i][j]);
        mx = red_max32(mx);
        const float hv = 0.5f * h[i];

        if (IS_QUERY) {
            const float hm = hv + mx;
            float q[8];
            #pragma unroll
            for (int j = 0; j < 8; ++j)
                q[j] = (__expf(acc[i][j] - hm) + EPS_PHI) * INV_SQRT_M;
            float4 o0 = {q[0], q[1], q[2], q[3]};
            float4 o1 = {q[4], q[5], q[6], q[7]};
            *(float4*)&out[(size_t)grow * MF + tx * 4]       = o0;
            *(float4*)&out[(size_t)grow * MF + 128 + tx * 4] = o1;
            float np = 0.f;
            #pragma unroll
            for (int j = 0; j < 4; ++j) {
                np = fmaf(q[j],     KsS[tx * 4 + j],       np);
                np = fmaf(q[4 + j], KsS[128 + tx * 4 + j], np);
            }
            np = red_sum32(np);
            if (tx == 0) aux[grow] = np;
        } else {
            float4 o0 = {acc[i][0] - hv, acc[i][1] - hv, acc[i][2] - hv, acc[i][3] - hv};
            float4 o1 = {acc[i][4] - hv, acc[i][5] - hv, acc[i][6] - hv, acc[i][7] - hv};
            *(float4*)&out[(size_t)grow * MF + tx * 4]       = o0;
            *(float4*)&out[(size_t)grow * MF + 128 + tx * 4] = o1;
            if (tx == 0) aux[grow] = mx;
        }
    }
}

// ---------------------------------------------------------------------------
// Kernel 2: segmax[b] = max over 512 rows of rmax
// ---------------------------------------------------------------------------
__global__ __launch_bounds__(256) void segmax_kernel(
    const float* __restrict__ rmax, float* __restrict__ segmax)
{
    const int b = blockIdx.x, tid = threadIdx.x;
    float v = fmaxf(rmax[b * NPB + tid], rmax[b * NPB + 256 + tid]);
    v = red_max32(v);
    v = fmaxf(v, __shfl_xor(v, 32, 64));
    __shared__ float red[4];
    if ((tid & 63) == 0) red[tid >> 6] = v;
    __syncthreads();
    if (tid == 0)
        segmax[b] = fmaxf(fmaxf(red[0], red[1]), fmaxf(red[2], red[3]));
}

// ---------------------------------------------------------------------------
// Kernel 3: partial KV: KVp[nt] = Kp[nt-slice]^T @ V[nt-slice].
// 128x128 tile, 8x8 micro, n-chunk 32, NS-way n-split for occupancy.
// PLAIN launch bounds (see LESSONS above). Swizzled LDS. vt==0 emits
// partial Ksum. grid.z = b*NS + nt.
// ---------------------------------------------------------------------------
template <int NS>
__global__ __launch_bounds__(256) void kv_kernel(
    const float* __restrict__ A, const float* __restrict__ V,
    const float* __restrict__ segmax,
    float* __restrict__ KVp, float* __restrict__ Ksump)
{
    __shared__ __align__(16) float Kps[32][128];
    __shared__ __align__(16) float Vs[32][128];

    const int tid = threadIdx.x;
    const int tx = tid & 15, ty = tid >> 4;
    const int vt = blockIdx.x, mt = blockIdx.y;
    const int b  = blockIdx.z / NS;
    const int nt = blockIdx.z % NS;
    const int m0 = mt * 128, v0 = vt * 128;
    const size_t n0 = (size_t)b * NPB + (size_t)nt * (NPB / NS);
    const float smax = segmax[b];

    const int ln  = tid >> 5;     // 0..7
    const int lm4 = tid & 31;     // float4 column slot (logical)

    float acc[8][8] = {};
    float4 ks4 = {0.f, 0.f, 0.f, 0.f};

    float4 areg[4], vreg[4];
    #pragma unroll
    for (int j = 0; j < 4; ++j) {
        const size_t n = n0 + ln + 8 * j;
        areg[j] = *(const float4*)&A[n * MF + m0 + lm4 * 4];
        vreg[j] = *(const float4*)&V[n * DVV + v0 + lm4 * 4];
    }

    const int NCHUNK = (NPB / NS) / 32;
    for (int c = 0; c < NCHUNK; ++c) {
        __syncthreads();
        #pragma unroll
        for (int j = 0; j < 4; ++j) {
            float4 e;
            e.x = (__expf(areg[j].x - smax) + EPS_PHI) * INV_SQRT_M;
            e.y = (__expf(areg[j].y - smax) + EPS_PHI) * INV_SQRT_M;
            e.z = (__expf(areg[j].z - smax) + EPS_PHI) * INV_SQRT_M;
            e.w = (__expf(areg[j].w - smax) + EPS_PHI) * INV_SQRT_M;
            ks4.x += e.x; ks4.y += e.y; ks4.z += e.z; ks4.w += e.w;
            *(float4*)&Kps[ln + 8 * j][SW(lm4) * 4] = e;
            *(float4*)&Vs[ln + 8 * j][SW(lm4) * 4]  = vreg[j];
        }
        __syncthreads();
        if (c < NCHUNK - 1) {
            #pragma unroll
            for (int j = 0; j < 4; ++j) {
                const size_t n = n0 + (c + 1) * 32 + ln + 8 * j;
                areg[j] = *(const float4*)&A[n * MF + m0 + lm4 * 4];
                vreg[j] = *(const float4*)&V[n * DVV + v0 + lm4 * 4];
            }
        }
        #pragma unroll 8
        for (int kk = 0; kk < 32; ++kk) {
            float4 a0 = *(const float4*)&Kps[kk][SW(ty * 2) * 4];
            float4 a1 = *(const float4*)&Kps[kk][SW(ty * 2 + 1) * 4];
            float4 b0 = *(const float4*)&Vs[kk][SW(tx * 2) * 4];
            float4 b1 = *(const float4*)&Vs[kk][SW(tx * 2 + 1) * 4];
            float av[8] = {a0.x, a0.y, a0.z, a0.w, a1.x, a1.y, a1.z, a1.w};
            float bv[8] = {b0.x, b0.y, b0.z, b0.w, b1.x, b1.y, b1.z, b1.w};
            #pragma unroll
            for (int i = 0; i < 8; ++i)
                #pragma unroll
                for (int j = 0; j < 8; ++j)
                    acc[i][j] = fmaf(av[i], bv[j], acc[i][j]);
        }
    }

    float* KVo = KVp + (size_t)nt * NB * MF * DVV;
    #pragma unroll
    for (int i = 0; i < 8; ++i) {
        float4 o0 = {acc[i][0], acc[i][1], acc[i][2], acc[i][3]};
        float4 o1 = {acc[i][4], acc[i][5], acc[i][6], acc[i][7]};
        const size_t base = ((size_t)b * MF + m0 + ty * 8 + i) * DVV + v0 + tx * 8;
        *(float4*)&KVo[base]     = o0;
        *(float4*)&KVo[base + 4] = o1;
    }

    if (vt == 0) {
        __syncthreads();
        *(float4*)&Kps[ln][SW(lm4) * 4] = ks4;     // scratch [8][128]
        __syncthreads();
        if (tid < 128) {
            float s = 0.f;
            #pragma unroll
            for (int g = 0; g < 8; ++g)
                s += Kps[g][SW(tid >> 2) * 4 + (tid & 3)];
            Ksump[(size_t)nt * NB * MF + b * MF + m0 + tid] = s;
        }
    }
}

// ---------------------------------------------------------------------------
// Kernel 3b: reduce NS partials: KV = sum_nt KVp[nt], Ksum = sum_nt Ksump[nt].
// ---------------------------------------------------------------------------
template <int NS>
__global__ __launch_bounds__(256) void reduce_kernel(
    const float* __restrict__ KVp, const float* __restrict__ Ksump,
    float* __restrict__ KV, float* __restrict__ Ksum)
{
    const int tid = threadIdx.x;
    if (blockIdx.x < 2048) {
        const float4* p = (const float4*)KVp;
        float4* o = (float4*)KV;
        const int gid = blockIdx.x * 256 + tid;
        #pragma unroll
        for (int j = 0; j < 2; ++j) {
            const size_t i = gid + 524288 * (size_t)j;
            float4 a = p[i];
            #pragma unroll
            for (int s = 1; s < NS; ++s) {
                float4 bq = p[i + (size_t)s * 1048576];
                a.x += bq.x; a.y += bq.y; a.z += bq.z; a.w += bq.w;
            }
            o[i] = a;
        }
    } else {
        const float4* p = (const float4*)Ksump;
        float4* o = (float4*)Ksum;
        const int t = (blockIdx.x - 2048) * 256 + tid;
        float4 a = p[t];
        #pragma unroll
        for (int s = 1; s < NS; ++s) {
            float4 bq = p[t + s * 4096];
            a.x += bq.x; a.y += bq.y; a.z += bq.z; a.w += bq.w;
        }
        o[t] = a;
    }
}

// ---------------------------------------------------------------------------
// Kernel 4 (rebuilt, kv-style): out = (Qp @ KV[b]) / (norm + eps).
// 128 rows x 128 v per block, 8x8 micro: rows = ty + 16*i, cols = split
// {tx*4..+3, 64+tx*4..+3}. m-chunk 32 (8 chunks). LDS 35.3 KB on purpose
// (4-block occupancy target -> 128-VGPR budget, see LESSON 2).
// Qp (HBM stream) register-prefetched; KV (16.8 MB, L2-hot) staged direct.
// grid (2, 4, 64) = 512 blocks.
// ---------------------------------------------------------------------------
__global__ __launch_bounds__(256) void out_kernel(
    const float* __restrict__ Qp, const float* __restrict__ KVm,
    const float* __restrict__ normv, float* __restrict__ out)
{
    __shared__ __align__(16) float Qs[128][36];   // row-major, stride 9 f4
    __shared__ __align__(16) float KVs[32][128];  // k-major
    __shared__ float nrmS[128];

    const int tid = threadIdx.x;
    const int tx = tid & 15, ty = tid >> 4;
    const int vt = blockIdx.x, rt = blockIdx.y, b = blockIdx.z;
    const int v0 = vt * 128;
    const int r0 = b * NPB + rt * 128;

    if (tid < 128) nrmS[tid] = normv[r0 + tid];

    const int qr  = tid >> 3;          // 0..31 (+32j)
    const int qm4 = tid & 7;           // f4 col within 32-k chunk
    const int kr  = tid >> 5;          // 0..7  (+8j)
    const int kc4 = tid & 31;          // f4 col within 128 v

    float acc[8][8] = {};

    float4 qreg[4];
    #pragma unroll
    for (int j = 0; j < 4; ++j)
        qreg[j] = *(const float4*)&Qp[(size_t)(r0 + qr + 32 * j) * MF + qm4 * 4];

    for (int c = 0; c < 8; ++c) {
        const int mc = c * 32;
        // KV staged directly (L2-hot) - no cross-chunk prefetch, saves regs
        float4 kreg[4];
        #pragma unroll
        for (int j = 0; j < 4; ++j)
            kreg[j] = *(const float4*)&KVm[((size_t)b * MF + mc + kr + 8 * j) * DVV + v0 + kc4 * 4];
        __syncthreads();
        #pragma unroll
        for (int j = 0; j < 4; ++j) {
            *(float4*)&Qs[qr + 32 * j][qm4 * 4]  = qreg[j];
            *(float4*)&KVs[kr + 8 * j][kc4 * 4] = kreg[j];
        }
        __syncthreads();
        if (c < 7) {
            const int mn = mc + 32;
            #pragma unroll
            for (int j = 0; j < 4; ++j)
                qreg[j] = *(const float4*)&Qp[(size_t)(r0 + qr + 32 * j) * MF + mn + qm4 * 4];
        }
        #pragma unroll
        for (int kq = 0; kq < 8; ++kq) {
            float4 a4[8];
            #pragma unroll
            for (int i = 0; i < 8; ++i)
                a4[i] = *(const float4*)&Qs[ty + 16 * i][kq * 4];
            #pragma unroll
            for (int t = 0; t < 4; ++t) {
                const int kk = kq * 4 + t;
                float4 b0 = *(const float4*)&KVs[kk][tx * 4];
                float4 b1 = *(const float4*)&KVs[kk][64 + tx * 4];
                float bv[8] = {b0.x, b0.y, b0.z, b0.w, b1.x, b1.y, b1.z, b1.w};
                #pragma unroll
                for (int i = 0; i < 8; ++i) {
                    const float av = ((const float*)&a4[i])[t];
                    #pragma unroll
                    for (int j = 0; j < 8; ++j)
                        acc[i][j] = fmaf(av, bv[j], acc[i][j]);
                }
            }
        }
    }

    #pragma unroll
    for (int i = 0; i < 8; ++i) {
        const int r = ty + 16 * i;
        const float inv = 1.0f / (nrmS[r] + EPS_NORM);
        float4 o0 = {acc[i][0] * inv, acc[i][1] * inv, acc[i][2] * inv, acc[i][3] * inv};
        float4 o1 = {acc[i][4] * inv, acc[i][5] * inv, acc[i][6] * inv, acc[i][7] * inv};
        *(float4*)&out[(size_t)(r0 + r) * DVV + v0 + tx * 4]      = o0;
        *(float4*)&out[(size_t)(r0 + r) * DVV + v0 + 64 + tx * 4] = o1;
    }
}

// ---------------------------------------------------------------------------
extern "C" void kernel_launch(void* const* d_in, const int* in_sizes, int n_in,
                              void* d_out, int out_size, void* d_ws, size_t ws_size,
                              hipStream_t stream)
{
    const float* Q     = (const float*)d_in[0];
    const float* K     = (const float*)d_in[1];
    const float* V     = (const float*)d_in[2];
    const float* omega = (const float*)d_in[3];
    float* out = (float*)d_out;

    const size_t KVSZ = (size_t)NB * MF * DVV;           // 4,194,304 floats
    const size_t need4 = ((size_t)NTOT * MF
                        + 4 * KVSZ
                        + 5 * (size_t)NB * MF
                        + 2 * NTOT + NB) * sizeof(float);
    const int NS = (ws_size >= need4) ? 4 : 2;

    float* ws    = (float*)d_ws;
    float* A     = ws;                                   // N*M; KV aliases after kv
    float* KV    = ws;                                   // aliases A (A dead post-kv)
    float* KVp   = A + (size_t)NTOT * MF;                // NS * B*M*DV
    float* Qp    = KVp;                                  // aliases KVp (dead post-reduce)
    float* Ksump = KVp + (size_t)NS * KVSZ;              // NS * B*M
    float* Ksum  = Ksump + (size_t)NS * NB * MF;         // B*M
    float* rmaxA = Ksum + (size_t)NB * MF;               // N
    float* smax  = rmaxA + NTOT;                         // B
    float* normv = smax + NB;                            // N

    phi_kernel<false><<<NTOT / 64, 256, 0, stream>>>(K, omega, (const float*)nullptr, A, rmaxA);
    segmax_kernel<<<NB, 256, 0, stream>>>(rmaxA, smax);
    if (NS == 4) {
        kv_kernel<4><<<dim3(2, 2, NB * 4), 256, 0, stream>>>(A, V, smax, KVp, Ksump);
        reduce_kernel<4><<<2064, 256, 0, stream>>>(KVp, Ksump, KV, Ksum);
    } else {
        kv_kernel<2><<<dim3(2, 2, NB * 2), 256, 0, stream>>>(A, V, smax, KVp, Ksump);
        reduce_kernel<2><<<2064, 256, 0, stream>>>(KVp, Ksump, KV, Ksum);
    }
    phi_kernel<true ><<<NTOT / 64, 256, 0, stream>>>(Q, omega, Ksum, Qp, normv);
    out_kernel<<<dim3(2, 4, NB), 256, 0, stream>>>(Qp, KV, normv, out);
}